// Round 15
// baseline (179.588 us; speedup 1.0000x reference)
//
#include <hip/hip_runtime.h>
#include <hip/hip_bf16.h>

typedef _Float16 half8 __attribute__((ext_vector_type(8)));
typedef __fp16 fp16x2 __attribute__((ext_vector_type(2)));
typedef float f32x4 __attribute__((ext_vector_type(4)));

#define B_ 8
#define U_ 1024
#define N_ 2048
#define DIN 128
#define H_ 4
#define HD 32
#define S_ 3072
#define LOG2E 1.44269504f
#define NU (B_ * U_ * 128)            // 1048576

// ---------------- phase 0+1 merged: mask packing || projections ----------------
// Blocks 0..6143: adjacency -> tiled bitmasks (HBM-bound).
// Blocks 6144..7679: projections + e + tiled V (compute/sync-bound).
// Independent work in one grid -> the 134MB adjacency stream overlaps the
// projection phase instead of serializing before it.
__global__ __launch_bounds__(256) void p01_kernel(
    const int* __restrict__ adj,
    const float* __restrict__ uf, const float* __restrict__ nf,
    const float* __restrict__ Wu, const float* __restrict__ Wn,
    const float* __restrict__ a_un, const float* __restrict__ a_nu,
    unsigned int* __restrict__ mA, unsigned int* __restrict__ mB,
    _Float16* __restrict__ vtA, _Float16* __restrict__ vtB,
    float* __restrict__ eRowA, float* __restrict__ eColA,
    float* __restrict__ eRowB, float* __restrict__ eColB)
{
  const int bid0 = blockIdx.x;
  const int tid = threadIdx.x;
  if (bid0 < 6144) {
    // ---------------- p0 role: adjacency -> bitmasks ----------------
    const int task = bid0 * 4 + (tid >> 6);
    const int l = tid & 63;
    const int* rowp;
    unsigned int* mOut;
    int iters;
    if (task < 8192) {                    // A-dir: user rows x news cols
      int b = task >> 10, r = task & 1023;
      rowp = adj + ((size_t)b * S_ + r) * S_ + U_;
      iters = 32;
      mOut = mA + ((size_t)(b * 64 + (r >> 4)) * 64) * 16 + (r & 15);
    } else {                              // B-dir: news rows x user cols
      int t2 = task - 8192;
      int b = t2 >> 11, r = t2 & 2047;
      rowp = adj + ((size_t)b * S_ + U_ + r) * S_;
      iters = 16;
      mOut = mB + ((size_t)(b * 128 + (r >> 4)) * 32) * 16 + (r & 15);
    }
    #pragma unroll 4
    for (int it = 0; it < iters; ++it) {
      int av = rowp[it * 64 + l];
      unsigned long long m = __ballot(av != 0);
      if (l == 0) {
        mOut[(2 * it) * 16]     = (unsigned int)m;
        mOut[(2 * it + 1) * 16] = (unsigned int)(m >> 32);
      }
    }
    return;
  }
  // ---------------- p1 role: projections + raw e + tiled f16 V ----------------
  __shared__ float fs[64][132];
  __shared__ float WsT[32][132];
  __shared__ float qt[32][65];
  __shared__ float aAs[32], aBs[32];

  const int bid = bid0 - 6144;
  int b, rt, R, h;
  const float *feat, *W;
  _Float16* vt;
  float *eA, *eB;
  int aAoff, aBoff;
  const float *avA, *avB;
  if (bid < 512) {                       // users: 8b x 16rt x 4h
    h = bid & 3; int t2 = bid >> 2; b = t2 >> 4; rt = t2 & 15; R = U_;
    feat = uf; W = Wu; vt = vtB;
    eA = eRowA; eB = eColB;
    avA = a_un; aAoff = 0;  avB = a_nu; aBoff = HD;
  } else {                               // news: 8b x 32rt x 4h
    int t3 = bid - 512;
    h = t3 & 3; int t2 = t3 >> 2; b = t2 >> 5; rt = t2 & 31; R = N_;
    feat = nf; W = Wn; vt = vtA;
    eA = eColA; eB = eRowB;
    avA = a_un; aAoff = HD; avB = a_nu; aBoff = 0;
  }
  const int r0 = rt * 64;

  const float4* feat4 = (const float4*)(feat + ((size_t)b * R + r0) * DIN);
  #pragma unroll
  for (int i = 0; i < 8; ++i) {
    int f4 = tid + 256 * i;
    int row = f4 >> 5, c4 = f4 & 31;
    *(float4*)&fs[row][c4 * 4] = feat4[row * 32 + c4];
  }
  {
    const float4* W4 = (const float4*)(W + (size_t)h * DIN * HD);
    #pragma unroll
    for (int i = 0; i < 4; ++i) {
      int f4 = tid + 256 * i;
      int d = f4 >> 3, kc = f4 & 7;
      float4 v = W4[f4];
      WsT[kc * 4 + 0][d] = v.x;
      WsT[kc * 4 + 1][d] = v.y;
      WsT[kc * 4 + 2][d] = v.z;
      WsT[kc * 4 + 3][d] = v.w;
    }
    if (tid < 32) {
      aAs[tid] = avA[h * 64 + aAoff + tid];
      aBs[tid] = avB[h * 64 + aBoff + tid];
    }
  }
  __syncthreads();

  const int kk = tid & 15, uu = tid >> 4;
  {
    float acc0[4] = {0.f, 0.f, 0.f, 0.f}, acc1[4] = {0.f, 0.f, 0.f, 0.f};
    #pragma unroll 8
    for (int d = 0; d < DIN; d += 4) {
      float4 w0 = *(const float4*)&WsT[kk][d];
      float4 w1 = *(const float4*)&WsT[kk + 16][d];
      #pragma unroll
      for (int i = 0; i < 4; ++i) {
        float4 fv = *(const float4*)&fs[uu + 16 * i][d];
        acc0[i] = fmaf(fv.x, w0.x, acc0[i]); acc0[i] = fmaf(fv.y, w0.y, acc0[i]);
        acc0[i] = fmaf(fv.z, w0.z, acc0[i]); acc0[i] = fmaf(fv.w, w0.w, acc0[i]);
        acc1[i] = fmaf(fv.x, w1.x, acc1[i]); acc1[i] = fmaf(fv.y, w1.y, acc1[i]);
        acc1[i] = fmaf(fv.z, w1.z, acc1[i]); acc1[i] = fmaf(fv.w, w1.w, acc1[i]);
      }
    }
    #pragma unroll
    for (int i = 0; i < 4; ++i) {
      qt[kk][uu + 16 * i] = acc0[i];
      qt[kk + 16][uu + 16 * i] = acc1[i];
    }
  }
  __syncthreads();

  const int u2 = tid & 63, part = tid >> 6;
  {
    size_t vtbase = (size_t)(b * H_ + h) * (R * HD)
                  + (size_t)((r0 >> 5) + (u2 >> 5)) * (HD * 32) + (u2 & 31);
    #pragma unroll
    for (int jj = 0; jj < 8; ++jj) {
      int krow = part * 8 + jj;
      vt[vtbase + krow * 32] = (_Float16)qt[krow][u2];
    }
  }
  if (part < 2) {
    float a_ = 0.f;
    const float* av = (part == 0) ? aAs : aBs;
    #pragma unroll
    for (int k2 = 0; k2 < HD; ++k2)
      a_ = fmaf(qt[k2][u2], av[k2], a_);
    float* e = (part == 0) ? eA : eB;
    e[(size_t)(b * H_ + h) * R + r0 + u2] = a_ * LOG2E;  // raw, log2e-scaled
  }
}

// ---------------- phase 2: 2-tile load-batched masked-softmax GEMM ----------------
// Barrier-free, LDS-free (masks pre-packed). Per iteration: issue ALL 10 loads
// for tiles {t, t+1}, sched_barrier(0) fence (stops the compiler sinking loads
// to their uses - the round-11/14 pipelines died that way), then compute both.
// Doubles outstanding misses per wave; fence placement still allows the
// compiler to hoist iteration i+1's batch above iteration i's compute.
__device__ __forceinline__ void wgen_mfma(
    unsigned int mb, float eq, const float4& e0, const float4& e1,
    const half8& v0, const half8& v1, half8 ones,
    f32x4& acc0, f32x4& acc1, f32x4& accd)
{
  float ecv[8] = {e0.x, e0.y, e0.z, e0.w, e1.x, e1.y, e1.z, e1.w};
  float wv[8];
  #pragma unroll
  for (int j = 0; j < 8; ++j) {
    float s  = eq + ecv[j];                 // log2e-scaled
    float ls = fmaxf(s, 0.2f * s);          // leaky
    ls = (mb & (1u << j)) ? ls : -1e9f;     // masked -> exp2 underflow to 0
    wv[j] = exp2f(ls);
  }
  union { fp16x2 h2[4]; half8 h8; } uw;
  uw.h2[0] = __builtin_amdgcn_cvt_pkrtz(wv[0], wv[1]);
  uw.h2[1] = __builtin_amdgcn_cvt_pkrtz(wv[2], wv[3]);
  uw.h2[2] = __builtin_amdgcn_cvt_pkrtz(wv[4], wv[5]);
  uw.h2[3] = __builtin_amdgcn_cvt_pkrtz(wv[6], wv[7]);
  half8 w = uw.h8;
  acc0 = __builtin_amdgcn_mfma_f32_16x16x32_f16(w, v0, acc0, 0, 0, 0);
  acc1 = __builtin_amdgcn_mfma_f32_16x16x32_f16(w, v1, acc1, 0, 0, 0);
  accd = __builtin_amdgcn_mfma_f32_16x16x32_f16(w, ones, accd, 0, 0, 0);
}

__global__ __launch_bounds__(256) void p2_kernel(
    const unsigned int* __restrict__ mA, const unsigned int* __restrict__ mB,
    const _Float16* __restrict__ vtA, const _Float16* __restrict__ vtB,
    const float* __restrict__ eRowA, const float* __restrict__ eColA,
    const float* __restrict__ eRowB, const float* __restrict__ eColB,
    const float* __restrict__ bn,
    float* __restrict__ numA, float* __restrict__ denA,
    float* __restrict__ out)
{
  const int tid = threadIdx.x;
  const int h = tid >> 6, l = tid & 63;
  const int row16 = l & 15;
  const int cg = (l >> 4) << 3;
  const int bid = blockIdx.x;

  f32x4 acc0 = {0.f,0.f,0.f,0.f}, acc1 = {0.f,0.f,0.f,0.f}, accd = {0.f,0.f,0.f,0.f};
  half8 ones = {(_Float16)1.f, (_Float16)1.f, (_Float16)1.f, (_Float16)1.f,
                (_Float16)1.f, (_Float16)1.f, (_Float16)1.f, (_Float16)1.f};

  const float* ecolH;
  const _Float16* vtb;
  const unsigned int* mT;
  float eq;
  int t0;
  if (bid < 1024) {                      // A-dir: b x rt(64) x half g
    const int b = bid & 7, rest = bid >> 3;
    const int rt = rest & 63, g = rest >> 6;
    eq = eRowA[(size_t)(b * H_ + h) * U_ + rt * 16 + row16];
    ecolH = eColA + (size_t)(b * H_ + h) * N_;
    vtb = vtA + (size_t)(b * H_ + h) * (N_ * HD);
    mT = mA + ((size_t)(b * 64 + rt) * 64) * 16;
    t0 = g * 32;
  } else {                               // B-dir: b x rt(128)
    const int t2 = bid - 1024;
    const int b = t2 & 7, rt = t2 >> 3;
    eq = eRowB[(size_t)(b * H_ + h) * N_ + rt * 16 + row16];
    ecolH = eColB + (size_t)(b * H_ + h) * U_;
    vtb = vtB + (size_t)(b * H_ + h) * (U_ * HD);
    mT = mB + ((size_t)(b * 128 + rt) * 32) * 16;
    t0 = 0;
  }

  for (int tt = 0; tt < 32; tt += 2) {
    const int ta = t0 + tt, tb = ta + 1;
    // ---- batched loads for BOTH tiles (10 independent loads in flight) ----
    unsigned int mwa = mT[ta * 16 + row16];
    unsigned int mwb = mT[tb * 16 + row16];
    const int cba = ta * 32 + cg, cbb = tb * 32 + cg;
    float4 ea0 = *(const float4*)(ecolH + cba);
    float4 ea1 = *(const float4*)(ecolH + cba + 4);
    float4 eb0 = *(const float4*)(ecolH + cbb);
    float4 eb1 = *(const float4*)(ecolH + cbb + 4);
    half8 va0 = *(const half8*)(vtb + ta * (HD * 32) + row16 * 32 + cg);
    half8 va1 = *(const half8*)(vtb + ta * (HD * 32) + (row16 + 16) * 32 + cg);
    half8 vb0 = *(const half8*)(vtb + tb * (HD * 32) + row16 * 32 + cg);
    half8 vb1 = *(const half8*)(vtb + tb * (HD * 32) + (row16 + 16) * 32 + cg);
    __builtin_amdgcn_sched_barrier(0);   // loads may not sink below this point
    // ---- compute both tiles ----
    wgen_mfma(mwa >> cg, eq, ea0, ea1, va0, va1, ones, acc0, acc1, accd);
    wgen_mfma(mwb >> cg, eq, eb0, eb1, vb0, vb1, ones, acc0, acc1, accd);
  }

  const int colk = row16;
  const int g4 = (l >> 4) << 2;
  if (bid < 1024) {                      // A-dir: store partials (combined in p3)
    const int b = bid & 7, rest = bid >> 3;
    const int rt = rest & 63, g = rest >> 6;
    #pragma unroll
    for (int q = 0; q < 4; ++q) {
      int orow = rt * 16 + g4 + q;
      size_t o = (((size_t)(g * 8 + b) * H_ + h) * U_ + orow) * 32 + colk;
      numA[o] = acc0[q];
      numA[o + 16] = acc1[q];
      if (colk == 0) denA[((size_t)(g * 8 + b) * H_ + h) * U_ + orow] = accd[q];
    }
  } else {                               // B-dir: fused epilogue direct to out
    const int t2 = bid - 1024;
    const int b = t2 & 7, rt = t2 >> 3;
    #pragma unroll
    for (int q = 0; q < 4; ++q) {
      int orow = rt * 16 + g4 + q;
      size_t o = ((size_t)(b * H_ + h) * N_ + orow) * 32 + colk;
      float den = accd[q];
      float v0 = acc0[q] / den + bn[q * 32 + colk];
      float v1 = acc1[q] / den + bn[q * 32 + colk + 16];
      out[NU + o]      = v0 > 0.f ? v0 : 0.f;
      out[NU + o + 16] = v1 > 0.f ? v1 : 0.f;
    }
  }
}

// ---------------- phase 3: combine A halves, divide, bias, relu (unchanged) ----------------
__global__ __launch_bounds__(256) void p3_kernel(
    const float* __restrict__ numA, const float* __restrict__ denA,
    const float* __restrict__ bu, float* __restrict__ out)
{
  int idx = blockIdx.x * 256 + threadIdx.x;
  float n = numA[idx] + numA[idx + NU];
  int dr = idx >> 5;
  float d = denA[dr] + denA[dr + B_ * H_ * U_];
  float v = n / d + bu[idx & 127];
  out[idx] = v > 0.f ? v : 0.f;
}

extern "C" void kernel_launch(void* const* d_in, const int* in_sizes, int n_in,
                              void* d_out, int out_size, void* d_ws, size_t ws_size,
                              hipStream_t stream) {
  const float* uf  = (const float*)d_in[0];
  const float* nf  = (const float*)d_in[1];
  const int*   adj = (const int*)d_in[2];
  const float* Wu  = (const float*)d_in[3];
  const float* Wn  = (const float*)d_in[4];
  const float* aun = (const float*)d_in[5];
  const float* anu = (const float*)d_in[6];
  const float* bu  = (const float*)d_in[7];
  const float* bn  = (const float*)d_in[8];

  char* ws = (char*)d_ws;
  size_t off = 0;
  _Float16* vtA = (_Float16*)(ws + off); off += (size_t)B_ * H_ * HD * N_ * 2;  // 4 MB
  _Float16* vtB = (_Float16*)(ws + off); off += (size_t)B_ * H_ * HD * U_ * 2;  // 2 MB
  float* eRowA = (float*)(ws + off); off += (size_t)B_ * H_ * U_ * 4;
  float* eColA = (float*)(ws + off); off += (size_t)B_ * H_ * N_ * 4;
  float* eRowB = (float*)(ws + off); off += (size_t)B_ * H_ * N_ * 4;
  float* eColB = (float*)(ws + off); off += (size_t)B_ * H_ * U_ * 4;
  unsigned int* mA = (unsigned int*)(ws + off); off += (size_t)B_ * 64 * 64 * 16 * 4;  // 2 MB
  unsigned int* mB = (unsigned int*)(ws + off); off += (size_t)B_ * 128 * 32 * 16 * 4; // 2 MB
  float* numA = (float*)(ws + off); off += (size_t)2 * NU * 4;                         // 8 MB
  float* denA = (float*)(ws + off); off += (size_t)2 * B_ * H_ * U_ * 4;
  (void)off; (void)ws_size; (void)in_sizes; (void)n_in; (void)out_size;        // ~19.7 MB

  p01_kernel<<<6144 + 1536, 256, 0, stream>>>(adj, uf, nf, Wu, Wn, aun, anu,
                                              mA, mB, vtA, vtB,
                                              eRowA, eColA, eRowB, eColB);
  p2_kernel<<<2048, 256, 0, stream>>>(mA, mB, vtA, vtB, eRowA, eColA,
                                      eRowB, eColB, bn, numA, denA, (float*)d_out);
  p3_kernel<<<NU / 256, 256, 0, stream>>>(numA, denA, bu, (float*)d_out);
}

// Round 16
// 122.518 us; speedup vs baseline: 1.4658x; 1.4658x over previous
//
#include <hip/hip_runtime.h>
#include <hip/hip_bf16.h>

typedef _Float16 half8 __attribute__((ext_vector_type(8)));
typedef __fp16 fp16x2 __attribute__((ext_vector_type(2)));
typedef float f32x4 __attribute__((ext_vector_type(4)));

#define B_ 8
#define U_ 1024
#define N_ 2048
#define DIN 128
#define H_ 4
#define HD 32
#define S_ 3072
#define LOG2E 1.44269504f
#define NU (B_ * U_ * 128)            // 1048576

// ---------------- phase 0: adjacency -> tiled global bitmasks (round-13 version) ----------------
// SEPARATE launch: merging this HBM-streaming role with p1's 58KB-LDS role
// capped it at 2 blocks/CU and collapsed stream BW 6.3->0.6 TB/s (round 15).
__global__ __launch_bounds__(256) void p0_kernel(
    const int* __restrict__ adj,
    unsigned int* __restrict__ mA, unsigned int* __restrict__ mB)
{
  const int task = blockIdx.x * 4 + (threadIdx.x >> 6);
  const int l = threadIdx.x & 63;
  const int* rowp;
  unsigned int* mOut;
  int iters;
  if (task < 8192) {                    // A-dir: user rows x news cols
    int b = task >> 10, r = task & 1023;
    rowp = adj + ((size_t)b * S_ + r) * S_ + U_;
    iters = 32;
    mOut = mA + ((size_t)(b * 64 + (r >> 4)) * 64) * 16 + (r & 15);
  } else {                              // B-dir: news rows x user cols
    int t2 = task - 8192;
    int b = t2 >> 11, r = t2 & 2047;
    rowp = adj + ((size_t)b * S_ + U_ + r) * S_;
    iters = 16;
    mOut = mB + ((size_t)(b * 128 + (r >> 4)) * 32) * 16 + (r & 15);
  }
  #pragma unroll 4
  for (int it = 0; it < iters; ++it) {
    int av = rowp[it * 64 + l];
    unsigned long long m = __ballot(av != 0);
    if (l == 0) {
      mOut[(2 * it) * 16]     = (unsigned int)m;
      mOut[(2 * it + 1) * 16] = (unsigned int)(m >> 32);
    }
  }
}

// ---------------- phase 1: projections + raw e + tiled f16 V (round-13 version) ----------------
__global__ __launch_bounds__(256) void p1_kernel(
    const float* __restrict__ uf, const float* __restrict__ nf,
    const float* __restrict__ Wu, const float* __restrict__ Wn,
    const float* __restrict__ a_un, const float* __restrict__ a_nu,
    _Float16* __restrict__ vtA, _Float16* __restrict__ vtB,
    float* __restrict__ eRowA, float* __restrict__ eColA,
    float* __restrict__ eRowB, float* __restrict__ eColB)
{
  __shared__ float fs[64][132];
  __shared__ float WsT[32][132];
  __shared__ float qt[32][65];
  __shared__ float aAs[32], aBs[32];

  const int bid = blockIdx.x;
  const int tid = threadIdx.x;

  int b, rt, R, h;
  const float *feat, *W;
  _Float16* vt;
  float *eA, *eB;
  int aAoff, aBoff;
  const float *avA, *avB;
  if (bid < 512) {                       // users: 8b x 16rt x 4h
    h = bid & 3; int t2 = bid >> 2; b = t2 >> 4; rt = t2 & 15; R = U_;
    feat = uf; W = Wu; vt = vtB;
    eA = eRowA; eB = eColB;
    avA = a_un; aAoff = 0;  avB = a_nu; aBoff = HD;
  } else {                               // news: 8b x 32rt x 4h
    int t3 = bid - 512;
    h = t3 & 3; int t2 = t3 >> 2; b = t2 >> 5; rt = t2 & 31; R = N_;
    feat = nf; W = Wn; vt = vtA;
    eA = eColA; eB = eRowB;
    avA = a_un; aAoff = HD; avB = a_nu; aBoff = 0;
  }
  const int r0 = rt * 64;

  const float4* feat4 = (const float4*)(feat + ((size_t)b * R + r0) * DIN);
  #pragma unroll
  for (int i = 0; i < 8; ++i) {
    int f4 = tid + 256 * i;
    int row = f4 >> 5, c4 = f4 & 31;
    *(float4*)&fs[row][c4 * 4] = feat4[row * 32 + c4];
  }
  {
    const float4* W4 = (const float4*)(W + (size_t)h * DIN * HD);
    #pragma unroll
    for (int i = 0; i < 4; ++i) {
      int f4 = tid + 256 * i;
      int d = f4 >> 3, kc = f4 & 7;
      float4 v = W4[f4];
      WsT[kc * 4 + 0][d] = v.x;
      WsT[kc * 4 + 1][d] = v.y;
      WsT[kc * 4 + 2][d] = v.z;
      WsT[kc * 4 + 3][d] = v.w;
    }
    if (tid < 32) {
      aAs[tid] = avA[h * 64 + aAoff + tid];
      aBs[tid] = avB[h * 64 + aBoff + tid];
    }
  }
  __syncthreads();

  const int kk = tid & 15, uu = tid >> 4;
  {
    float acc0[4] = {0.f, 0.f, 0.f, 0.f}, acc1[4] = {0.f, 0.f, 0.f, 0.f};
    #pragma unroll 8
    for (int d = 0; d < DIN; d += 4) {
      float4 w0 = *(const float4*)&WsT[kk][d];
      float4 w1 = *(const float4*)&WsT[kk + 16][d];
      #pragma unroll
      for (int i = 0; i < 4; ++i) {
        float4 fv = *(const float4*)&fs[uu + 16 * i][d];
        acc0[i] = fmaf(fv.x, w0.x, acc0[i]); acc0[i] = fmaf(fv.y, w0.y, acc0[i]);
        acc0[i] = fmaf(fv.z, w0.z, acc0[i]); acc0[i] = fmaf(fv.w, w0.w, acc0[i]);
        acc1[i] = fmaf(fv.x, w1.x, acc1[i]); acc1[i] = fmaf(fv.y, w1.y, acc1[i]);
        acc1[i] = fmaf(fv.z, w1.z, acc1[i]); acc1[i] = fmaf(fv.w, w1.w, acc1[i]);
      }
    }
    #pragma unroll
    for (int i = 0; i < 4; ++i) {
      qt[kk][uu + 16 * i] = acc0[i];
      qt[kk + 16][uu + 16 * i] = acc1[i];
    }
  }
  __syncthreads();

  const int u2 = tid & 63, part = tid >> 6;
  {
    size_t vtbase = (size_t)(b * H_ + h) * (R * HD)
                  + (size_t)((r0 >> 5) + (u2 >> 5)) * (HD * 32) + (u2 & 31);
    #pragma unroll
    for (int jj = 0; jj < 8; ++jj) {
      int krow = part * 8 + jj;
      vt[vtbase + krow * 32] = (_Float16)qt[krow][u2];
    }
  }
  if (part < 2) {
    float a_ = 0.f;
    const float* av = (part == 0) ? aAs : aBs;
    #pragma unroll
    for (int k2 = 0; k2 < HD; ++k2)
      a_ = fmaf(qt[k2][u2], av[k2], a_);
    float* e = (part == 0) ? eA : eB;
    e[(size_t)(b * H_ + h) * R + r0 + u2] = a_ * LOG2E;  // raw, log2e-scaled
  }
}

// ---------------- phase 2: 2-tile load-batched masked-softmax GEMM ----------------
// Barrier-free, LDS-free. Per iteration: issue ALL 10 loads for tiles {t,t+1},
// sched_barrier(0) fence (stops the compiler sinking loads to uses), compute both.
__device__ __forceinline__ void wgen_mfma(
    unsigned int mb, float eq, const float4& e0, const float4& e1,
    const half8& v0, const half8& v1, half8 ones,
    f32x4& acc0, f32x4& acc1, f32x4& accd)
{
  float ecv[8] = {e0.x, e0.y, e0.z, e0.w, e1.x, e1.y, e1.z, e1.w};
  float wv[8];
  #pragma unroll
  for (int j = 0; j < 8; ++j) {
    float s  = eq + ecv[j];                 // log2e-scaled
    float ls = fmaxf(s, 0.2f * s);          // leaky
    ls = (mb & (1u << j)) ? ls : -1e9f;     // masked -> exp2 underflow to 0
    wv[j] = exp2f(ls);
  }
  union { fp16x2 h2[4]; half8 h8; } uw;
  uw.h2[0] = __builtin_amdgcn_cvt_pkrtz(wv[0], wv[1]);
  uw.h2[1] = __builtin_amdgcn_cvt_pkrtz(wv[2], wv[3]);
  uw.h2[2] = __builtin_amdgcn_cvt_pkrtz(wv[4], wv[5]);
  uw.h2[3] = __builtin_amdgcn_cvt_pkrtz(wv[6], wv[7]);
  half8 w = uw.h8;
  acc0 = __builtin_amdgcn_mfma_f32_16x16x32_f16(w, v0, acc0, 0, 0, 0);
  acc1 = __builtin_amdgcn_mfma_f32_16x16x32_f16(w, v1, acc1, 0, 0, 0);
  accd = __builtin_amdgcn_mfma_f32_16x16x32_f16(w, ones, accd, 0, 0, 0);
}

__global__ __launch_bounds__(256) void p2_kernel(
    const unsigned int* __restrict__ mA, const unsigned int* __restrict__ mB,
    const _Float16* __restrict__ vtA, const _Float16* __restrict__ vtB,
    const float* __restrict__ eRowA, const float* __restrict__ eColA,
    const float* __restrict__ eRowB, const float* __restrict__ eColB,
    const float* __restrict__ bn,
    float* __restrict__ numA, float* __restrict__ denA,
    float* __restrict__ out)
{
  const int tid = threadIdx.x;
  const int h = tid >> 6, l = tid & 63;
  const int row16 = l & 15;
  const int cg = (l >> 4) << 3;
  const int bid = blockIdx.x;

  f32x4 acc0 = {0.f,0.f,0.f,0.f}, acc1 = {0.f,0.f,0.f,0.f}, accd = {0.f,0.f,0.f,0.f};
  half8 ones = {(_Float16)1.f, (_Float16)1.f, (_Float16)1.f, (_Float16)1.f,
                (_Float16)1.f, (_Float16)1.f, (_Float16)1.f, (_Float16)1.f};

  const float* ecolH;
  const _Float16* vtb;
  const unsigned int* mT;
  float eq;
  int t0;
  if (bid < 1024) {                      // A-dir: b x rt(64) x half g
    const int b = bid & 7, rest = bid >> 3;
    const int rt = rest & 63, g = rest >> 6;
    eq = eRowA[(size_t)(b * H_ + h) * U_ + rt * 16 + row16];
    ecolH = eColA + (size_t)(b * H_ + h) * N_;
    vtb = vtA + (size_t)(b * H_ + h) * (N_ * HD);
    mT = mA + ((size_t)(b * 64 + rt) * 64) * 16;
    t0 = g * 32;
  } else {                               // B-dir: b x rt(128)
    const int t2 = bid - 1024;
    const int b = t2 & 7, rt = t2 >> 3;
    eq = eRowB[(size_t)(b * H_ + h) * N_ + rt * 16 + row16];
    ecolH = eColB + (size_t)(b * H_ + h) * U_;
    vtb = vtB + (size_t)(b * H_ + h) * (U_ * HD);
    mT = mB + ((size_t)(b * 128 + rt) * 32) * 16;
    t0 = 0;
  }

  for (int tt = 0; tt < 32; tt += 2) {
    const int ta = t0 + tt, tb = ta + 1;
    // ---- batched loads for BOTH tiles (10 independent loads in flight) ----
    unsigned int mwa = mT[ta * 16 + row16];
    unsigned int mwb = mT[tb * 16 + row16];
    const int cba = ta * 32 + cg, cbb = tb * 32 + cg;
    float4 ea0 = *(const float4*)(ecolH + cba);
    float4 ea1 = *(const float4*)(ecolH + cba + 4);
    float4 eb0 = *(const float4*)(ecolH + cbb);
    float4 eb1 = *(const float4*)(ecolH + cbb + 4);
    half8 va0 = *(const half8*)(vtb + ta * (HD * 32) + row16 * 32 + cg);
    half8 va1 = *(const half8*)(vtb + ta * (HD * 32) + (row16 + 16) * 32 + cg);
    half8 vb0 = *(const half8*)(vtb + tb * (HD * 32) + row16 * 32 + cg);
    half8 vb1 = *(const half8*)(vtb + tb * (HD * 32) + (row16 + 16) * 32 + cg);
    __builtin_amdgcn_sched_barrier(0);   // loads may not sink below this point
    // ---- compute both tiles ----
    wgen_mfma(mwa >> cg, eq, ea0, ea1, va0, va1, ones, acc0, acc1, accd);
    wgen_mfma(mwb >> cg, eq, eb0, eb1, vb0, vb1, ones, acc0, acc1, accd);
  }

  const int colk = row16;
  const int g4 = (l >> 4) << 2;
  if (bid < 1024) {                      // A-dir: store partials (combined in p3)
    const int b = bid & 7, rest = bid >> 3;
    const int rt = rest & 63, g = rest >> 6;
    #pragma unroll
    for (int q = 0; q < 4; ++q) {
      int orow = rt * 16 + g4 + q;
      size_t o = (((size_t)(g * 8 + b) * H_ + h) * U_ + orow) * 32 + colk;
      numA[o] = acc0[q];
      numA[o + 16] = acc1[q];
      if (colk == 0) denA[((size_t)(g * 8 + b) * H_ + h) * U_ + orow] = accd[q];
    }
  } else {                               // B-dir: fused epilogue direct to out
    const int t2 = bid - 1024;
    const int b = t2 & 7, rt = t2 >> 3;
    #pragma unroll
    for (int q = 0; q < 4; ++q) {
      int orow = rt * 16 + g4 + q;
      size_t o = ((size_t)(b * H_ + h) * N_ + orow) * 32 + colk;
      float den = accd[q];
      float v0 = acc0[q] / den + bn[q * 32 + colk];
      float v1 = acc1[q] / den + bn[q * 32 + colk + 16];
      out[NU + o]      = v0 > 0.f ? v0 : 0.f;
      out[NU + o + 16] = v1 > 0.f ? v1 : 0.f;
    }
  }
}

// ---------------- phase 3: combine A halves, divide, bias, relu ----------------
__global__ __launch_bounds__(256) void p3_kernel(
    const float* __restrict__ numA, const float* __restrict__ denA,
    const float* __restrict__ bu, float* __restrict__ out)
{
  int idx = blockIdx.x * 256 + threadIdx.x;
  float n = numA[idx] + numA[idx + NU];
  int dr = idx >> 5;
  float d = denA[dr] + denA[dr + B_ * H_ * U_];
  float v = n / d + bu[idx & 127];
  out[idx] = v > 0.f ? v : 0.f;
}

extern "C" void kernel_launch(void* const* d_in, const int* in_sizes, int n_in,
                              void* d_out, int out_size, void* d_ws, size_t ws_size,
                              hipStream_t stream) {
  const float* uf  = (const float*)d_in[0];
  const float* nf  = (const float*)d_in[1];
  const int*   adj = (const int*)d_in[2];
  const float* Wu  = (const float*)d_in[3];
  const float* Wn  = (const float*)d_in[4];
  const float* aun = (const float*)d_in[5];
  const float* anu = (const float*)d_in[6];
  const float* bu  = (const float*)d_in[7];
  const float* bn  = (const float*)d_in[8];

  char* ws = (char*)d_ws;
  size_t off = 0;
  _Float16* vtA = (_Float16*)(ws + off); off += (size_t)B_ * H_ * HD * N_ * 2;  // 4 MB
  _Float16* vtB = (_Float16*)(ws + off); off += (size_t)B_ * H_ * HD * U_ * 2;  // 2 MB
  float* eRowA = (float*)(ws + off); off += (size_t)B_ * H_ * U_ * 4;
  float* eColA = (float*)(ws + off); off += (size_t)B_ * H_ * N_ * 4;
  float* eRowB = (float*)(ws + off); off += (size_t)B_ * H_ * N_ * 4;
  float* eColB = (float*)(ws + off); off += (size_t)B_ * H_ * U_ * 4;
  unsigned int* mA = (unsigned int*)(ws + off); off += (size_t)B_ * 64 * 64 * 16 * 4;  // 2 MB
  unsigned int* mB = (unsigned int*)(ws + off); off += (size_t)B_ * 128 * 32 * 16 * 4; // 2 MB
  float* numA = (float*)(ws + off); off += (size_t)2 * NU * 4;                         // 8 MB
  float* denA = (float*)(ws + off); off += (size_t)2 * B_ * H_ * U_ * 4;
  (void)off; (void)ws_size; (void)in_sizes; (void)n_in; (void)out_size;        // ~19.7 MB

  p0_kernel<<<6144, 256, 0, stream>>>(adj, mA, mB);
  p1_kernel<<<512 + 1024, 256, 0, stream>>>(uf, nf, Wu, Wn, aun, anu,
                                            vtA, vtB, eRowA, eColA, eRowB, eColB);
  p2_kernel<<<2048, 256, 0, stream>>>(mA, mB, vtA, vtB, eRowA, eColA,
                                      eRowB, eColB, bn, numA, denA, (float*)d_out);
  p3_kernel<<<NU / 256, 256, 0, stream>>>(numA, denA, bu, (float*)d_out);
}